// Round 16
// baseline (139.870 us; speedup 1.0000x reference)
//
#include <hip/hip_runtime.h>
#include <math.h>

// MHSA forward. x[16,1024,512]f32, w_qkv[512,1536], w_out[512,512], b_out[512].
// Round 16: R14 base (attn FROZEN — 4-wave/256-thr/stage-first is the only schedule that
// passes; R7/R8/R13/R15 all failed on restructures). GEMMs re-tiled 256x128, 8 waves
// (per-wave body identical: 64x64 out, acc[4][4], stage-first). prep unchanged.
// ws: qkvb bf16[16384,1536] | vT bf16[128,64,1024] | xb/aoutb bf16[16384,512] | wqkvT | woutT

#define QSCALE_ 0.06376541773f        // 512^-0.5 * log2(e)
#define RESCALE_THR_ 8.0f             // log2-domain defer-max threshold

typedef float f32x4 __attribute__((ext_vector_type(4)));
typedef __bf16 bf16x8 __attribute__((ext_vector_type(8)));

static __device__ __forceinline__ ushort bf_bits(float f) {
    unsigned u = __builtin_bit_cast(unsigned, f);
    u += 0x7fffu + ((u >> 16) & 1u);          // RNE
    return (ushort)(u >> 16);
}
static __device__ __forceinline__ unsigned cvt_pk_bf16(float lo, float hi) {
    unsigned d;
    asm("v_cvt_pk_bf16_f32 %0, %1, %2" : "=v"(d) : "v"(lo), "v"(hi));
    return d;
}
static __device__ __forceinline__ float fmax3_(float a, float b, float c) {
    return fmaxf(fmaxf(a, b), c);
}
// bijective XCD swizzle: consecutive logical ids land on the same XCD (requires nwg%8==0)
static __device__ __forceinline__ int xcd_logical(int bid, int nwg) {
    return (bid & 7) * (nwg >> 3) + (bid >> 3);
}

#define GLDS16(gsrc, ldst)                                                              \
    __builtin_amdgcn_global_load_lds((const __attribute__((address_space(1))) void*)(gsrc), \
                                     (__attribute__((address_space(3))) void*)(ldst), 16, 0, 0)

// ---------------- prep: x cast (blocks 0..8191) + weight transposes (8192..9215) ----------------
__global__ __launch_bounds__(256) void prep(const float* __restrict__ x,
                                            ushort* __restrict__ xb,
                                            const float* __restrict__ wqkv,
                                            ushort* __restrict__ wqkvT,
                                            const float* __restrict__ wout,
                                            ushort* __restrict__ woutT) {
    if (blockIdx.x < 8192) {
        const int i = blockIdx.x * 256 + threadIdx.x;   // 2097152 float4's
        const float4 v = ((const float4*)x)[i];
        ushort4 o;
        o.x = bf_bits(v.x); o.y = bf_bits(v.y); o.z = bf_bits(v.z); o.w = bf_bits(v.w);
        ((ushort4*)xb)[i] = o;
        return;
    }
    __shared__ float t[32][33];
    const int tx = threadIdx.x & 31, ty = threadIdx.x >> 5;
    const float* in;
    ushort* out;
    int n0, k0, N;
    float scale;
    int scaleRows;
    const int bid = blockIdx.x - 8192;
    if (bid < 768) {
        in = wqkv; out = wqkvT; N = 1536;
        n0 = (bid % 48) * 32; k0 = (bid / 48) * 32;
        scale = QSCALE_; scaleRows = 512;
    } else {
        in = wout; out = woutT; N = 512;
        const int b2 = bid - 768;
        n0 = (b2 % 16) * 32; k0 = (b2 / 16) * 32;
        scale = 1.f; scaleRows = 0;
    }
    for (int i = ty; i < 32; i += 8)
        t[i][tx] = in[(size_t)(k0 + i) * N + n0 + tx];
    __syncthreads();
    for (int i = ty; i < 32; i += 8) {
        const float s = (n0 + i < scaleRows) ? scale : 1.f;
        out[(size_t)(n0 + i) * 512 + k0 + tx] = bf_bits(t[tx][i] * s);
    }
}

// ---------------- C = A[M,K] @ BT[N,K]^T (+bias), bf16 MFMA, 256x128 tile, 8 waves ----------
// Per-wave body identical to the proven 128x128 kernel (64x64 out, acc[4][4], 16 MFMA/step).
// Stage-first double-buffer schedule (R12-proven order). LDS: A 2x16KB @0, B 2x8KB @32768.
// Cb path: cols >= 1024 (V region) divert to vT[bh=128][dv=64][n=1024] (when VT != null).
__global__ __launch_bounds__(512) void gemm_bf16(const ushort* __restrict__ A,
                                                 const ushort* __restrict__ BT,
                                                 const float* __restrict__ bias,
                                                 float* __restrict__ C,
                                                 ushort* __restrict__ Cb,
                                                 ushort* __restrict__ VT,
                                                 int M, int N, int K, int nx) {
    __shared__ __align__(16) char lds[49152];
    const int logical = xcd_logical(blockIdx.x, gridDim.x);
    const int bx = logical % nx;
    const int by = logical / nx;
    const int tid = threadIdx.x;
    const int lane = tid & 63;
    const int w = tid >> 6;             // 0..7
    const int wr = w >> 1, wc = w & 1;  // wave grid 4x2 -> 64-row x 64-col sub-tiles
    const int fr = lane & 15;
    const int fg = lane >> 4;
    const int rowBase = by * 256;
    const int colBase = bx * 128;

    auto stageG = [&](int k0, int buf) {
        // A tile [256][32] bf16 = 16KB: 2 rounds x 512 thr x 16B
#pragma unroll
        for (int r = 0; r < 2; ++r) {
            const unsigned boff = r * 8192u + w * 1024u + lane * 16u;
            const unsigned row = boff >> 6;
            const unsigned ke = (boff & 63u) >> 1;
            GLDS16(A + (size_t)(rowBase + row) * K + k0 + ke,
                   lds + buf * 16384 + r * 8192 + w * 1024);
        }
        // B tile [128][32] bf16 = 8KB: 1 round
        {
            const unsigned boff = w * 1024u + lane * 16u;
            const unsigned row = boff >> 6;
            const unsigned ke = (boff & 63u) >> 1;
            GLDS16(BT + (size_t)(colBase + row) * K + k0 + ke,
                   lds + 32768 + buf * 8192 + w * 1024);
        }
    };

    f32x4 acc[4][4] = {};

    stageG(0, 0);
    __syncthreads();
    int cur = 0;
    const int nsteps = K / 32;

    for (int s = 0; s < nsteps; ++s) {
        if (s + 1 < nsteps) stageG((s + 1) * 32, cur ^ 1);
        const char* ab = lds + cur * 16384;
        const char* bb = lds + 32768 + cur * 8192;

        bf16x8 a_frag[4], b_frag[4];
#pragma unroll
        for (int mi = 0; mi < 4; ++mi)
            a_frag[mi] = *(const bf16x8*)(ab + (wr * 64 + mi * 16 + fr) * 64 + fg * 16);
#pragma unroll
        for (int ni = 0; ni < 4; ++ni)
            b_frag[ni] = *(const bf16x8*)(bb + (wc * 64 + ni * 16 + fr) * 64 + fg * 16);
#pragma unroll
        for (int mi = 0; mi < 4; ++mi)
#pragma unroll
            for (int ni = 0; ni < 4; ++ni)
                acc[mi][ni] = __builtin_amdgcn_mfma_f32_16x16x32_bf16(a_frag[mi], b_frag[ni],
                                                                      acc[mi][ni], 0, 0, 0);
        __syncthreads();
        cur ^= 1;
    }

#pragma unroll
    for (int ni = 0; ni < 4; ++ni) {
        const int col = colBase + wc * 64 + ni * 16 + fr;
        const float bv = bias ? bias[col] : 0.f;
#pragma unroll
        for (int mi = 0; mi < 4; ++mi) {
            const int row0 = rowBase + wr * 64 + mi * 16 + fg * 4;
            if (Cb) {
                if (VT && col >= 1024) {
                    const int hd = col - 1024;
                    const size_t vb = ((size_t)((row0 >> 10) * 8 + (hd >> 6)) * 64 + (hd & 63)) * 1024
                                      + (row0 & 1023);
                    ushort4 pk4;
                    pk4.x = bf_bits(acc[mi][ni][0]);
                    pk4.y = bf_bits(acc[mi][ni][1]);
                    pk4.z = bf_bits(acc[mi][ni][2]);
                    pk4.w = bf_bits(acc[mi][ni][3]);
                    *(ushort4*)(VT + vb) = pk4;
                } else {
#pragma unroll
                    for (int q = 0; q < 4; ++q)
                        Cb[(size_t)(row0 + q) * N + col] = bf_bits(acc[mi][ni][q]);
                }
            } else {
#pragma unroll
                for (int q = 0; q < 4; ++q)
                    C[(size_t)(row0 + q) * N + col] = acc[mi][ni][q] + bv;
            }
        }
    }
}

// ---------------- MFMA flash attention (R14-FROZEN — do not restructure) ----------------
// 4 waves, 256 thr, 64-row Q tile, stage(t+1) FIRST in tile(). 1-D grid 2048, XCD-swizzled.
__global__ __launch_bounds__(256) void attn_mfma(const ushort* __restrict__ qkv,
                                                 const ushort* __restrict__ vT,
                                                 ushort* __restrict__ aoutb) {
    __shared__ __align__(16) char lds[40960];  // K:[2]x8KB @0 ; VT:[2]x8KB @16384 ; P: @32768 + w*2048
    const int logical = xcd_logical(blockIdx.x, gridDim.x);
    const int qt = logical & 15;
    const int bh = logical >> 4;
    const int b = bh >> 3, h = bh & 7;
    const int tid = threadIdx.x;
    const int lane = tid & 63;
    const int w = tid >> 6;
    const int fr = lane & 15;
    const int fg = lane >> 4;

    const size_t nbase = (size_t)b * 1024;
    const int qrow0 = qt * 64;

    bf16x8 qf[2];
    {
        const size_t qa = (nbase + qrow0 + w * 16 + fr) * 1536 + h * 64;
        qf[0] = *(const bf16x8*)(qkv + qa + fg * 8);
        qf[1] = *(const bf16x8*)(qkv + qa + 32 + fg * 8);
    }

    bf16x8 onesf;
#pragma unroll
    for (int e = 0; e < 8; ++e) onesf[e] = __builtin_bit_cast(__bf16, (ushort)0x3F80);

    const int srow = w * 16 + (lane >> 3);
    const int slot = lane & 7;
    auto stage = [&](int kt, int buf) {
        char* kd = lds + buf * 8192;
        char* vd = lds + 16384 + buf * 8192;
#pragma unroll
        for (int r = 0; r < 2; ++r) {
            const int row = srow + r * 8;
            const int sw = slot ^ (row & 7);
            GLDS16(qkv + (nbase + kt * 64 + row) * 1536 + 512 + h * 64 + sw * 8,
                   kd + (w * 2 + r) * 1024);
            GLDS16(vT + ((size_t)bh * 64 + row) * 1024 + kt * 64 + sw * 8,
                   vd + (w * 2 + r) * 1024);
        }
    };

    f32x4 o[4] = {};                      // o[dvb]: q = fg*4+r, dv = dvb*16+fr
    f32x4 lacc = {};                      // l[q = fg*4+r]
    float mrow = -INFINITY;               // running max for q = fr (log2 domain)

    stage(0, 0);
    __syncthreads();
    char* const pbase = lds + 32768 + w * 2048;   // per-wave P[16 q][64 k] bf16, swizzled

    auto tile = [&](int kt, int cur) {
        if (kt < 15) stage(kt + 1, cur ^ 1);
        const char* kb = lds + cur * 8192;
        const char* vb = lds + 16384 + cur * 8192;

        // ---- S^T = K Q^T : lane (fr,fg) holds S[k=jb*16+fg*4+r][q=fr] ----
        f32x4 S[4];
        __builtin_amdgcn_s_setprio(1);
#pragma unroll
        for (int jb = 0; jb < 4; ++jb) {
            f32x4 a = {};
#pragma unroll
            for (int s = 0; s < 2; ++s) {
                const int row = jb * 16 + fr;
                const int c = s * 64 + fg * 16;
                const bf16x8 kf = *(const bf16x8*)(kb + row * 128 + (c ^ ((row & 7) << 4)));
                a = __builtin_amdgcn_mfma_f32_16x16x32_bf16(kf, qf[s], a, 0, 0, 0);
            }
            S[jb] = a;
        }
        __builtin_amdgcn_s_setprio(0);

        // ---- row max: max3 tree + cross-fg combine ----
        float tmax = fmax3_(S[0][0], S[0][1], S[0][2]);
        tmax = fmax3_(tmax, S[0][3], S[1][0]);
        tmax = fmax3_(tmax, S[1][1], S[1][2]);
        tmax = fmax3_(tmax, S[1][3], S[2][0]);
        tmax = fmax3_(tmax, S[2][1], S[2][2]);
        tmax = fmax3_(tmax, S[2][3], S[3][0]);
        tmax = fmax3_(tmax, S[3][1], S[3][2]);
        tmax = fmaxf(tmax, S[3][3]);
        tmax = fmaxf(tmax, __shfl_xor(tmax, 16));
        tmax = fmaxf(tmax, __shfl_xor(tmax, 32));

        // ---- defer-max: rescale only when a row grew > THR ----
        if (!__all(tmax - mrow <= RESCALE_THR_)) {
            const float mnew = fmaxf(mrow, tmax);
            const float corr = __builtin_amdgcn_exp2f(mrow - mnew);
            mrow = mnew;
#pragma unroll
            for (int r = 0; r < 4; ++r) {
                const float cr = __shfl(corr, fg * 4 + r);
                lacc[r] *= cr;
#pragma unroll
                for (int dvb = 0; dvb < 4; ++dvb) o[dvb][r] *= cr;
            }
        }

        // ---- P = 2^(S - m), pack (arithmetic 64b build), stage to per-wave LDS ----
#pragma unroll
        for (int jb = 0; jb < 4; ++jb) {
            const unsigned lo = cvt_pk_bf16(__builtin_amdgcn_exp2f(S[jb][0] - mrow),
                                            __builtin_amdgcn_exp2f(S[jb][1] - mrow));
            const unsigned hi = cvt_pk_bf16(__builtin_amdgcn_exp2f(S[jb][2] - mrow),
                                            __builtin_amdgcn_exp2f(S[jb][3] - mrow));
            const unsigned long long pv =
                (unsigned long long)lo | ((unsigned long long)hi << 32);
            *(unsigned long long*)(pbase + fr * 128 +
                                   ((jb * 32 + fg * 8) ^ ((fr & 7) << 4))) = pv;
        }

        // ---- fence: keep P ds_writes ordered before pf ds_reads ----
        asm volatile("" ::: "memory");

        // ---- O += P V ; l += P 1 (row-sum via MFMA) ----
        __builtin_amdgcn_s_setprio(1);
#pragma unroll
        for (int s = 0; s < 2; ++s) {
            const int pc = s * 64 + fg * 16;
            const bf16x8 pf = *(const bf16x8*)(pbase + fr * 128 + (pc ^ ((fr & 7) << 4)));
            lacc = __builtin_amdgcn_mfma_f32_16x16x32_bf16(pf, onesf, lacc, 0, 0, 0);
#pragma unroll
            for (int dvb = 0; dvb < 4; ++dvb) {
                const int vrow = dvb * 16 + fr;
                const bf16x8 vf = *(const bf16x8*)(vb + vrow * 128 + (pc ^ ((vrow & 7) << 4)));
                o[dvb] = __builtin_amdgcn_mfma_f32_16x16x32_bf16(pf, vf, o[dvb], 0, 0, 0);
            }
        }
        __builtin_amdgcn_s_setprio(0);
        __syncthreads();
    };

    for (int kt = 0; kt < 16; kt += 2) {
        tile(kt, 0);
        tile(kt + 1, 1);
    }

    // ---- epilogue: l already indexed by this lane's o-rows (q = fg*4+r) ----
#pragma unroll
    for (int r = 0; r < 4; ++r) {
        const float linv = 1.f / lacc[r];
        const size_t n = nbase + qrow0 + w * 16 + fg * 4 + r;
#pragma unroll
        for (int dvb = 0; dvb < 4; ++dvb)
            aoutb[n * 512 + h * 64 + dvb * 16 + fr] = bf_bits(o[dvb][r] * linv);
    }
}

extern "C" void kernel_launch(void* const* d_in, const int* in_sizes, int n_in,
                              void* d_out, int out_size, void* d_ws, size_t ws_size,
                              hipStream_t stream) {
    const float* x     = (const float*)d_in[0];
    const float* w_qkv = (const float*)d_in[1];
    const float* w_out = (const float*)d_in[2];
    const float* b_out = (const float*)d_in[3];
    float* out = (float*)d_out;

    char* ws = (char*)d_ws;
    ushort* qkvb  = (ushort*)ws;                                  // 48 MiB [16384,1536] (V cols unused)
    ushort* vT    = (ushort*)(ws + 50331648);                     // 16 MiB [128,64,1024]
    ushort* xb    = (ushort*)(ws + 50331648 + 16777216);          // 16 MiB
    ushort* aoutb = xb;                                           // aliased (xb dead after GEMM1)
    ushort* wqkvT = (ushort*)(ws + 50331648 + 33554432);          // 1.5 MiB
    ushort* woutT = (ushort*)(ws + 50331648 + 33554432 + 1572864);// 0.5 MiB

    const dim3 blk(256);
    // x cast + both weight transposes, one dispatch
    prep<<<dim3(9216), blk, 0, stream>>>(x, xb, w_qkv, wqkvT, w_out, woutT);
    // qkv (bf16) = x @ w_qkv ; V columns divert to vT  (256x128 tiles, 8 waves)
    gemm_bf16<<<dim3(768), dim3(512), 0, stream>>>(xb, wqkvT, nullptr, nullptr, qkvb, vT,
                                                   16384, 1536, 512, 12);
    // attention (64-row q-tiles), XCD-swizzled — R14-frozen
    attn_mfma<<<dim3(2048), blk, 0, stream>>>(qkvb, vT, aoutb);
    // out = aout @ w_out + b_out (f32)  (256x128 tiles, 8 waves)
    gemm_bf16<<<dim3(256), dim3(512), 0, stream>>>(aoutb, woutT, b_out, out, nullptr, nullptr,
                                                   16384, 512, 512, 4);
}

// Round 17
// 136.158 us; speedup vs baseline: 1.0273x; 1.0273x over previous
//
#include <hip/hip_runtime.h>
#include <math.h>

// MHSA forward. x[16,1024,512]f32, w_qkv[512,1536], w_out[512,512], b_out[512].
// Round 17: R14 revert (GEMM 128x128/4-wave proven; R16's 256x128 regressed on occupancy).
// GEMM templated on WROWS: =64 is byte-identical R14 (GEMM1); =32 gives 64x128 tile for
// GEMM2 (grid 1024 = 4 WGs/CU vs 1). attn FROZEN (R14 schedule). prep unchanged.
// ws: qkvb bf16[16384,1536] | vT bf16[128,64,1024] | xb/aoutb bf16[16384,512] | wqkvT | woutT

#define QSCALE_ 0.06376541773f        // 512^-0.5 * log2(e)
#define RESCALE_THR_ 8.0f             // log2-domain defer-max threshold

typedef float f32x4 __attribute__((ext_vector_type(4)));
typedef __bf16 bf16x8 __attribute__((ext_vector_type(8)));

static __device__ __forceinline__ ushort bf_bits(float f) {
    unsigned u = __builtin_bit_cast(unsigned, f);
    u += 0x7fffu + ((u >> 16) & 1u);          // RNE
    return (ushort)(u >> 16);
}
static __device__ __forceinline__ unsigned cvt_pk_bf16(float lo, float hi) {
    unsigned d;
    asm("v_cvt_pk_bf16_f32 %0, %1, %2" : "=v"(d) : "v"(lo), "v"(hi));
    return d;
}
static __device__ __forceinline__ float fmax3_(float a, float b, float c) {
    return fmaxf(fmaxf(a, b), c);
}
// bijective XCD swizzle: consecutive logical ids land on the same XCD (requires nwg%8==0)
static __device__ __forceinline__ int xcd_logical(int bid, int nwg) {
    return (bid & 7) * (nwg >> 3) + (bid >> 3);
}

#define GLDS16(gsrc, ldst)                                                              \
    __builtin_amdgcn_global_load_lds((const __attribute__((address_space(1))) void*)(gsrc), \
                                     (__attribute__((address_space(3))) void*)(ldst), 16, 0, 0)

// ---------------- prep: x cast (blocks 0..8191) + weight transposes (8192..9215) ----------------
__global__ __launch_bounds__(256) void prep(const float* __restrict__ x,
                                            ushort* __restrict__ xb,
                                            const float* __restrict__ wqkv,
                                            ushort* __restrict__ wqkvT,
                                            const float* __restrict__ wout,
                                            ushort* __restrict__ woutT) {
    if (blockIdx.x < 8192) {
        const int i = blockIdx.x * 256 + threadIdx.x;   // 2097152 float4's
        const float4 v = ((const float4*)x)[i];
        ushort4 o;
        o.x = bf_bits(v.x); o.y = bf_bits(v.y); o.z = bf_bits(v.z); o.w = bf_bits(v.w);
        ((ushort4*)xb)[i] = o;
        return;
    }
    __shared__ float t[32][33];
    const int tx = threadIdx.x & 31, ty = threadIdx.x >> 5;
    const float* in;
    ushort* out;
    int n0, k0, N;
    float scale;
    int scaleRows;
    const int bid = blockIdx.x - 8192;
    if (bid < 768) {
        in = wqkv; out = wqkvT; N = 1536;
        n0 = (bid % 48) * 32; k0 = (bid / 48) * 32;
        scale = QSCALE_; scaleRows = 512;
    } else {
        in = wout; out = woutT; N = 512;
        const int b2 = bid - 768;
        n0 = (b2 % 16) * 32; k0 = (b2 / 16) * 32;
        scale = 1.f; scaleRows = 0;
    }
    for (int i = ty; i < 32; i += 8)
        t[i][tx] = in[(size_t)(k0 + i) * N + n0 + tx];
    __syncthreads();
    for (int i = ty; i < 32; i += 8) {
        const float s = (n0 + i < scaleRows) ? scale : 1.f;
        out[(size_t)(n0 + i) * 512 + k0 + tx] = bf_bits(t[tx][i] * s);
    }
}

// ---------------- C = A[M,K] @ BT[N,K]^T (+bias), bf16 MFMA, (2*WROWS)x128 tile ----------
// WROWS=64 -> byte-identical to the R14-proven 128x128 kernel. WROWS=32 -> 64x128 tile
// (1 A-staging round, 24KB LDS, acc[2][4]). Stage-first dbuf schedule (R12-proven order).
// Cb path: cols >= 1024 (V region) divert to vT[bh=128][dv=64][n=1024] (when VT != null).
template <int WROWS>
__global__ __launch_bounds__(256) void gemm_bf16(const ushort* __restrict__ A,
                                                 const ushort* __restrict__ BT,
                                                 const float* __restrict__ bias,
                                                 float* __restrict__ C,
                                                 ushort* __restrict__ Cb,
                                                 ushort* __restrict__ VT,
                                                 int M, int N, int K, int nx) {
    constexpr int MI = WROWS / 16;                 // frags per wave in M
    constexpr int AROUNDS = WROWS / 32;            // 4KB staging rounds for A
    constexpr int ATILE = WROWS * 128;             // A-tile bytes (2*WROWS rows x 32k x 2B)
    constexpr int BOFF = 2 * ATILE;                // B dbuf offset
    __shared__ __align__(16) char lds[BOFF + 16384];
    const int logical = xcd_logical(blockIdx.x, gridDim.x);
    const int bx = logical % nx;
    const int by = logical / nx;
    const int tid = threadIdx.x;
    const int lane = tid & 63;
    const int w = tid >> 6;
    const int wr = w >> 1, wc = w & 1;
    const int fr = lane & 15;
    const int fg = lane >> 4;
    const int rowBase = by * (2 * WROWS);
    const int colBase = bx * 128;

    auto stageG = [&](int k0, int buf) {
#pragma unroll
        for (int r = 0; r < AROUNDS; ++r) {
            const unsigned boff = r * 4096u + w * 1024u + lane * 16u;
            const unsigned row = boff >> 6;
            const unsigned ke = (boff & 63u) >> 1;
            GLDS16(A + (size_t)(rowBase + row) * K + k0 + ke,
                   lds + buf * ATILE + r * 4096 + w * 1024);
        }
#pragma unroll
        for (int r = 0; r < 2; ++r) {
            const unsigned boff = r * 4096u + w * 1024u + lane * 16u;
            const unsigned row = boff >> 6;
            const unsigned ke = (boff & 63u) >> 1;
            GLDS16(BT + (size_t)(colBase + row) * K + k0 + ke,
                   lds + BOFF + buf * 8192 + r * 4096 + w * 1024);
        }
    };

    f32x4 acc[MI][4] = {};

    stageG(0, 0);
    __syncthreads();
    int cur = 0;
    const int nsteps = K / 32;

    for (int s = 0; s < nsteps; ++s) {
        if (s + 1 < nsteps) stageG((s + 1) * 32, cur ^ 1);
        const char* ab = lds + cur * ATILE;
        const char* bb = lds + BOFF + cur * 8192;

        bf16x8 a_frag[MI], b_frag[4];
#pragma unroll
        for (int mi = 0; mi < MI; ++mi)
            a_frag[mi] = *(const bf16x8*)(ab + (wr * WROWS + mi * 16 + fr) * 64 + fg * 16);
#pragma unroll
        for (int ni = 0; ni < 4; ++ni)
            b_frag[ni] = *(const bf16x8*)(bb + (wc * 64 + ni * 16 + fr) * 64 + fg * 16);
#pragma unroll
        for (int mi = 0; mi < MI; ++mi)
#pragma unroll
            for (int ni = 0; ni < 4; ++ni)
                acc[mi][ni] = __builtin_amdgcn_mfma_f32_16x16x32_bf16(a_frag[mi], b_frag[ni],
                                                                      acc[mi][ni], 0, 0, 0);
        __syncthreads();
        cur ^= 1;
    }

#pragma unroll
    for (int ni = 0; ni < 4; ++ni) {
        const int col = colBase + wc * 64 + ni * 16 + fr;
        const float bv = bias ? bias[col] : 0.f;
#pragma unroll
        for (int mi = 0; mi < MI; ++mi) {
            const int row0 = rowBase + wr * WROWS + mi * 16 + fg * 4;
            if (Cb) {
                if (VT && col >= 1024) {
                    const int hd = col - 1024;
                    const size_t vb = ((size_t)((row0 >> 10) * 8 + (hd >> 6)) * 64 + (hd & 63)) * 1024
                                      + (row0 & 1023);
                    ushort4 pk4;
                    pk4.x = bf_bits(acc[mi][ni][0]);
                    pk4.y = bf_bits(acc[mi][ni][1]);
                    pk4.z = bf_bits(acc[mi][ni][2]);
                    pk4.w = bf_bits(acc[mi][ni][3]);
                    *(ushort4*)(VT + vb) = pk4;
                } else {
#pragma unroll
                    for (int q = 0; q < 4; ++q)
                        Cb[(size_t)(row0 + q) * N + col] = bf_bits(acc[mi][ni][q]);
                }
            } else {
#pragma unroll
                for (int q = 0; q < 4; ++q)
                    C[(size_t)(row0 + q) * N + col] = acc[mi][ni][q] + bv;
            }
        }
    }
}

// ---------------- MFMA flash attention (R14-FROZEN — do not restructure) ----------------
// 4 waves, 256 thr, 64-row Q tile, stage(t+1) FIRST in tile(). 1-D grid 2048, XCD-swizzled.
__global__ __launch_bounds__(256) void attn_mfma(const ushort* __restrict__ qkv,
                                                 const ushort* __restrict__ vT,
                                                 ushort* __restrict__ aoutb) {
    __shared__ __align__(16) char lds[40960];  // K:[2]x8KB @0 ; VT:[2]x8KB @16384 ; P: @32768 + w*2048
    const int logical = xcd_logical(blockIdx.x, gridDim.x);
    const int qt = logical & 15;
    const int bh = logical >> 4;
    const int b = bh >> 3, h = bh & 7;
    const int tid = threadIdx.x;
    const int lane = tid & 63;
    const int w = tid >> 6;
    const int fr = lane & 15;
    const int fg = lane >> 4;

    const size_t nbase = (size_t)b * 1024;
    const int qrow0 = qt * 64;

    bf16x8 qf[2];
    {
        const size_t qa = (nbase + qrow0 + w * 16 + fr) * 1536 + h * 64;
        qf[0] = *(const bf16x8*)(qkv + qa + fg * 8);
        qf[1] = *(const bf16x8*)(qkv + qa + 32 + fg * 8);
    }

    bf16x8 onesf;
#pragma unroll
    for (int e = 0; e < 8; ++e) onesf[e] = __builtin_bit_cast(__bf16, (ushort)0x3F80);

    const int srow = w * 16 + (lane >> 3);
    const int slot = lane & 7;
    auto stage = [&](int kt, int buf) {
        char* kd = lds + buf * 8192;
        char* vd = lds + 16384 + buf * 8192;
#pragma unroll
        for (int r = 0; r < 2; ++r) {
            const int row = srow + r * 8;
            const int sw = slot ^ (row & 7);
            GLDS16(qkv + (nbase + kt * 64 + row) * 1536 + 512 + h * 64 + sw * 8,
                   kd + (w * 2 + r) * 1024);
            GLDS16(vT + ((size_t)bh * 64 + row) * 1024 + kt * 64 + sw * 8,
                   vd + (w * 2 + r) * 1024);
        }
    };

    f32x4 o[4] = {};                      // o[dvb]: q = fg*4+r, dv = dvb*16+fr
    f32x4 lacc = {};                      // l[q = fg*4+r]
    float mrow = -INFINITY;               // running max for q = fr (log2 domain)

    stage(0, 0);
    __syncthreads();
    char* const pbase = lds + 32768 + w * 2048;   // per-wave P[16 q][64 k] bf16, swizzled

    auto tile = [&](int kt, int cur) {
        if (kt < 15) stage(kt + 1, cur ^ 1);
        const char* kb = lds + cur * 8192;
        const char* vb = lds + 16384 + cur * 8192;

        // ---- S^T = K Q^T : lane (fr,fg) holds S[k=jb*16+fg*4+r][q=fr] ----
        f32x4 S[4];
        __builtin_amdgcn_s_setprio(1);
#pragma unroll
        for (int jb = 0; jb < 4; ++jb) {
            f32x4 a = {};
#pragma unroll
            for (int s = 0; s < 2; ++s) {
                const int row = jb * 16 + fr;
                const int c = s * 64 + fg * 16;
                const bf16x8 kf = *(const bf16x8*)(kb + row * 128 + (c ^ ((row & 7) << 4)));
                a = __builtin_amdgcn_mfma_f32_16x16x32_bf16(kf, qf[s], a, 0, 0, 0);
            }
            S[jb] = a;
        }
        __builtin_amdgcn_s_setprio(0);

        // ---- row max: max3 tree + cross-fg combine ----
        float tmax = fmax3_(S[0][0], S[0][1], S[0][2]);
        tmax = fmax3_(tmax, S[0][3], S[1][0]);
        tmax = fmax3_(tmax, S[1][1], S[1][2]);
        tmax = fmax3_(tmax, S[1][3], S[2][0]);
        tmax = fmax3_(tmax, S[2][1], S[2][2]);
        tmax = fmax3_(tmax, S[2][3], S[3][0]);
        tmax = fmax3_(tmax, S[3][1], S[3][2]);
        tmax = fmaxf(tmax, S[3][3]);
        tmax = fmaxf(tmax, __shfl_xor(tmax, 16));
        tmax = fmaxf(tmax, __shfl_xor(tmax, 32));

        // ---- defer-max: rescale only when a row grew > THR ----
        if (!__all(tmax - mrow <= RESCALE_THR_)) {
            const float mnew = fmaxf(mrow, tmax);
            const float corr = __builtin_amdgcn_exp2f(mrow - mnew);
            mrow = mnew;
#pragma unroll
            for (int r = 0; r < 4; ++r) {
                const float cr = __shfl(corr, fg * 4 + r);
                lacc[r] *= cr;
#pragma unroll
                for (int dvb = 0; dvb < 4; ++dvb) o[dvb][r] *= cr;
            }
        }

        // ---- P = 2^(S - m), pack (arithmetic 64b build), stage to per-wave LDS ----
#pragma unroll
        for (int jb = 0; jb < 4; ++jb) {
            const unsigned lo = cvt_pk_bf16(__builtin_amdgcn_exp2f(S[jb][0] - mrow),
                                            __builtin_amdgcn_exp2f(S[jb][1] - mrow));
            const unsigned hi = cvt_pk_bf16(__builtin_amdgcn_exp2f(S[jb][2] - mrow),
                                            __builtin_amdgcn_exp2f(S[jb][3] - mrow));
            const unsigned long long pv =
                (unsigned long long)lo | ((unsigned long long)hi << 32);
            *(unsigned long long*)(pbase + fr * 128 +
                                   ((jb * 32 + fg * 8) ^ ((fr & 7) << 4))) = pv;
        }

        // ---- fence: keep P ds_writes ordered before pf ds_reads ----
        asm volatile("" ::: "memory");

        // ---- O += P V ; l += P 1 (row-sum via MFMA) ----
        __builtin_amdgcn_s_setprio(1);
#pragma unroll
        for (int s = 0; s < 2; ++s) {
            const int pc = s * 64 + fg * 16;
            const bf16x8 pf = *(const bf16x8*)(pbase + fr * 128 + (pc ^ ((fr & 7) << 4)));
            lacc = __builtin_amdgcn_mfma_f32_16x16x32_bf16(pf, onesf, lacc, 0, 0, 0);
#pragma unroll
            for (int dvb = 0; dvb < 4; ++dvb) {
                const int vrow = dvb * 16 + fr;
                const bf16x8 vf = *(const bf16x8*)(vb + vrow * 128 + (pc ^ ((vrow & 7) << 4)));
                o[dvb] = __builtin_amdgcn_mfma_f32_16x16x32_bf16(pf, vf, o[dvb], 0, 0, 0);
            }
        }
        __builtin_amdgcn_s_setprio(0);
        __syncthreads();
    };

    for (int kt = 0; kt < 16; kt += 2) {
        tile(kt, 0);
        tile(kt + 1, 1);
    }

    // ---- epilogue: l already indexed by this lane's o-rows (q = fg*4+r) ----
#pragma unroll
    for (int r = 0; r < 4; ++r) {
        const float linv = 1.f / lacc[r];
        const size_t n = nbase + qrow0 + w * 16 + fg * 4 + r;
#pragma unroll
        for (int dvb = 0; dvb < 4; ++dvb)
            aoutb[n * 512 + h * 64 + dvb * 16 + fr] = bf_bits(o[dvb][r] * linv);
    }
}

extern "C" void kernel_launch(void* const* d_in, const int* in_sizes, int n_in,
                              void* d_out, int out_size, void* d_ws, size_t ws_size,
                              hipStream_t stream) {
    const float* x     = (const float*)d_in[0];
    const float* w_qkv = (const float*)d_in[1];
    const float* w_out = (const float*)d_in[2];
    const float* b_out = (const float*)d_in[3];
    float* out = (float*)d_out;

    char* ws = (char*)d_ws;
    ushort* qkvb  = (ushort*)ws;                                  // 48 MiB [16384,1536] (V cols unused)
    ushort* vT    = (ushort*)(ws + 50331648);                     // 16 MiB [128,64,1024]
    ushort* xb    = (ushort*)(ws + 50331648 + 16777216);          // 16 MiB
    ushort* aoutb = xb;                                           // aliased (xb dead after GEMM1)
    ushort* wqkvT = (ushort*)(ws + 50331648 + 33554432);          // 1.5 MiB
    ushort* woutT = (ushort*)(ws + 50331648 + 33554432 + 1572864);// 0.5 MiB

    const dim3 blk(256);
    // x cast + both weight transposes, one dispatch
    prep<<<dim3(9216), blk, 0, stream>>>(x, xb, w_qkv, wqkvT, w_out, woutT);
    // qkv (bf16) = x @ w_qkv ; V columns divert to vT  (128x128, R14-proven instantiation)
    gemm_bf16<64><<<dim3(1536), blk, 0, stream>>>(xb, wqkvT, nullptr, nullptr, qkvb, vT,
                                                  16384, 1536, 512, 12);
    // attention (64-row q-tiles), XCD-swizzled — R14-frozen
    attn_mfma<<<dim3(2048), blk, 0, stream>>>(qkvb, vT, aoutb);
    // out = aout @ w_out + b_out (f32)  (64x128 tiles -> 1024 WGs = 4/CU)
    gemm_bf16<32><<<dim3(1024), blk, 0, stream>>>(aoutb, woutT, b_out, out, nullptr, nullptr,
                                                  16384, 512, 512, 4);
}

// Round 18
// 135.240 us; speedup vs baseline: 1.0342x; 1.0068x over previous
//
#include <hip/hip_runtime.h>
#include <math.h>

// MHSA forward. x[16,1024,512]f32, w_qkv[512,1536], w_out[512,512], b_out[512].
// Round 18: final config = R14-exact (best proven, 134.6us). prep (fused cast+transposes),
// GEMMs 128x128/4-wave dbuf stage-first + XCD swizzle, attn 4-wave/64-row FROZEN schedule.
// Session ledger: attn restructures (2-qb, reorder, 8-wave) all fail correctness — the
// P-LDS pipeline is schedule-brittle; 256-tile & WROWS=32 GEMMs regress/neutral.
// ws: qkvb bf16[16384,1536] | vT bf16[128,64,1024] | xb/aoutb bf16[16384,512] | wqkvT | woutT

#define QSCALE_ 0.06376541773f        // 512^-0.5 * log2(e)
#define RESCALE_THR_ 8.0f             // log2-domain defer-max threshold

typedef float f32x4 __attribute__((ext_vector_type(4)));
typedef __bf16 bf16x8 __attribute__((ext_vector_type(8)));

static __device__ __forceinline__ ushort bf_bits(float f) {
    unsigned u = __builtin_bit_cast(unsigned, f);
    u += 0x7fffu + ((u >> 16) & 1u);          // RNE
    return (ushort)(u >> 16);
}
static __device__ __forceinline__ unsigned cvt_pk_bf16(float lo, float hi) {
    unsigned d;
    asm("v_cvt_pk_bf16_f32 %0, %1, %2" : "=v"(d) : "v"(lo), "v"(hi));
    return d;
}
static __device__ __forceinline__ float fmax3_(float a, float b, float c) {
    return fmaxf(fmaxf(a, b), c);
}
// bijective XCD swizzle: consecutive logical ids land on the same XCD (requires nwg%8==0)
static __device__ __forceinline__ int xcd_logical(int bid, int nwg) {
    return (bid & 7) * (nwg >> 3) + (bid >> 3);
}

#define GLDS16(gsrc, ldst)                                                              \
    __builtin_amdgcn_global_load_lds((const __attribute__((address_space(1))) void*)(gsrc), \
                                     (__attribute__((address_space(3))) void*)(ldst), 16, 0, 0)

// ---------------- prep: x cast (blocks 0..8191) + weight transposes (8192..9215) ----------------
__global__ __launch_bounds__(256) void prep(const float* __restrict__ x,
                                            ushort* __restrict__ xb,
                                            const float* __restrict__ wqkv,
                                            ushort* __restrict__ wqkvT,
                                            const float* __restrict__ wout,
                                            ushort* __restrict__ woutT) {
    if (blockIdx.x < 8192) {
        const int i = blockIdx.x * 256 + threadIdx.x;   // 2097152 float4's
        const float4 v = ((const float4*)x)[i];
        ushort4 o;
        o.x = bf_bits(v.x); o.y = bf_bits(v.y); o.z = bf_bits(v.z); o.w = bf_bits(v.w);
        ((ushort4*)xb)[i] = o;
        return;
    }
    __shared__ float t[32][33];
    const int tx = threadIdx.x & 31, ty = threadIdx.x >> 5;
    const float* in;
    ushort* out;
    int n0, k0, N;
    float scale;
    int scaleRows;
    const int bid = blockIdx.x - 8192;
    if (bid < 768) {
        in = wqkv; out = wqkvT; N = 1536;
        n0 = (bid % 48) * 32; k0 = (bid / 48) * 32;
        scale = QSCALE_; scaleRows = 512;
    } else {
        in = wout; out = woutT; N = 512;
        const int b2 = bid - 768;
        n0 = (b2 % 16) * 32; k0 = (b2 / 16) * 32;
        scale = 1.f; scaleRows = 0;
    }
    for (int i = ty; i < 32; i += 8)
        t[i][tx] = in[(size_t)(k0 + i) * N + n0 + tx];
    __syncthreads();
    for (int i = ty; i < 32; i += 8) {
        const float s = (n0 + i < scaleRows) ? scale : 1.f;
        out[(size_t)(n0 + i) * 512 + k0 + tx] = bf_bits(t[tx][i] * s);
    }
}

// ---------------- C = A[M,K] @ BT[N,K]^T (+bias), bf16 MFMA, 128x128, dbuf ----------------
// R12/R14-proven schedule: stage(t+1) issued FIRST, then frag reads. Do not reorder.
// Cb path: cols >= 1024 (V region) divert to vT[bh=128][dv=64][n=1024] (when VT != null).
__global__ __launch_bounds__(256) void gemm_bf16(const ushort* __restrict__ A,
                                                 const ushort* __restrict__ BT,
                                                 const float* __restrict__ bias,
                                                 float* __restrict__ C,
                                                 ushort* __restrict__ Cb,
                                                 ushort* __restrict__ VT,
                                                 int M, int N, int K, int nx) {
    __shared__ __align__(16) char lds[32768];
    const int logical = xcd_logical(blockIdx.x, gridDim.x);
    const int bx = logical % nx;
    const int by = logical / nx;
    const int tid = threadIdx.x;
    const int lane = tid & 63;
    const int w = tid >> 6;
    const int wr = w >> 1, wc = w & 1;
    const int fr = lane & 15;
    const int fg = lane >> 4;
    const int rowBase = by * 128;
    const int colBase = bx * 128;

    auto stageG = [&](int k0, int buf) {
#pragma unroll
        for (int r = 0; r < 2; ++r) {
            const unsigned boff = r * 4096u + w * 1024u + lane * 16u;
            const unsigned row = boff >> 6;
            const unsigned ke = (boff & 63u) >> 1;
            GLDS16(A + (size_t)(rowBase + row) * K + k0 + ke,
                   lds + buf * 8192 + r * 4096 + w * 1024);
            GLDS16(BT + (size_t)(colBase + row) * K + k0 + ke,
                   lds + 16384 + buf * 8192 + r * 4096 + w * 1024);
        }
    };

    f32x4 acc[4][4] = {};

    stageG(0, 0);
    __syncthreads();
    int cur = 0;
    const int nsteps = K / 32;

    for (int s = 0; s < nsteps; ++s) {
        if (s + 1 < nsteps) stageG((s + 1) * 32, cur ^ 1);
        const char* ab = lds + cur * 8192;
        const char* bb = lds + 16384 + cur * 8192;

        bf16x8 a_frag[4], b_frag[4];
#pragma unroll
        for (int mi = 0; mi < 4; ++mi)
            a_frag[mi] = *(const bf16x8*)(ab + (wr * 64 + mi * 16 + fr) * 64 + fg * 16);
#pragma unroll
        for (int ni = 0; ni < 4; ++ni)
            b_frag[ni] = *(const bf16x8*)(bb + (wc * 64 + ni * 16 + fr) * 64 + fg * 16);
#pragma unroll
        for (int mi = 0; mi < 4; ++mi)
#pragma unroll
            for (int ni = 0; ni < 4; ++ni)
                acc[mi][ni] = __builtin_amdgcn_mfma_f32_16x16x32_bf16(a_frag[mi], b_frag[ni],
                                                                      acc[mi][ni], 0, 0, 0);
        __syncthreads();
        cur ^= 1;
    }

#pragma unroll
    for (int ni = 0; ni < 4; ++ni) {
        const int col = colBase + wc * 64 + ni * 16 + fr;
        const float bv = bias ? bias[col] : 0.f;
#pragma unroll
        for (int mi = 0; mi < 4; ++mi) {
            const int row0 = rowBase + wr * 64 + mi * 16 + fg * 4;
            if (Cb) {
                if (VT && col >= 1024) {
                    const int hd = col - 1024;
                    const size_t vb = ((size_t)((row0 >> 10) * 8 + (hd >> 6)) * 64 + (hd & 63)) * 1024
                                      + (row0 & 1023);
                    ushort4 pk4;
                    pk4.x = bf_bits(acc[mi][ni][0]);
                    pk4.y = bf_bits(acc[mi][ni][1]);
                    pk4.z = bf_bits(acc[mi][ni][2]);
                    pk4.w = bf_bits(acc[mi][ni][3]);
                    *(ushort4*)(VT + vb) = pk4;
                } else {
#pragma unroll
                    for (int q = 0; q < 4; ++q)
                        Cb[(size_t)(row0 + q) * N + col] = bf_bits(acc[mi][ni][q]);
                }
            } else {
#pragma unroll
                for (int q = 0; q < 4; ++q)
                    C[(size_t)(row0 + q) * N + col] = acc[mi][ni][q] + bv;
            }
        }
    }
}

// ---------------- MFMA flash attention (R14-FROZEN — do not restructure) ----------------
// 4 waves, 256 thr, 64-row Q tile, stage(t+1) FIRST in tile(). 1-D grid 2048, XCD-swizzled.
__global__ __launch_bounds__(256) void attn_mfma(const ushort* __restrict__ qkv,
                                                 const ushort* __restrict__ vT,
                                                 ushort* __restrict__ aoutb) {
    __shared__ __align__(16) char lds[40960];  // K:[2]x8KB @0 ; VT:[2]x8KB @16384 ; P: @32768 + w*2048
    const int logical = xcd_logical(blockIdx.x, gridDim.x);
    const int qt = logical & 15;
    const int bh = logical >> 4;
    const int b = bh >> 3, h = bh & 7;
    const int tid = threadIdx.x;
    const int lane = tid & 63;
    const int w = tid >> 6;
    const int fr = lane & 15;
    const int fg = lane >> 4;

    const size_t nbase = (size_t)b * 1024;
    const int qrow0 = qt * 64;

    bf16x8 qf[2];
    {
        const size_t qa = (nbase + qrow0 + w * 16 + fr) * 1536 + h * 64;
        qf[0] = *(const bf16x8*)(qkv + qa + fg * 8);
        qf[1] = *(const bf16x8*)(qkv + qa + 32 + fg * 8);
    }

    bf16x8 onesf;
#pragma unroll
    for (int e = 0; e < 8; ++e) onesf[e] = __builtin_bit_cast(__bf16, (ushort)0x3F80);

    const int srow = w * 16 + (lane >> 3);
    const int slot = lane & 7;
    auto stage = [&](int kt, int buf) {
        char* kd = lds + buf * 8192;
        char* vd = lds + 16384 + buf * 8192;
#pragma unroll
        for (int r = 0; r < 2; ++r) {
            const int row = srow + r * 8;
            const int sw = slot ^ (row & 7);
            GLDS16(qkv + (nbase + kt * 64 + row) * 1536 + 512 + h * 64 + sw * 8,
                   kd + (w * 2 + r) * 1024);
            GLDS16(vT + ((size_t)bh * 64 + row) * 1024 + kt * 64 + sw * 8,
                   vd + (w * 2 + r) * 1024);
        }
    };

    f32x4 o[4] = {};                      // o[dvb]: q = fg*4+r, dv = dvb*16+fr
    f32x4 lacc = {};                      // l[q = fg*4+r]
    float mrow = -INFINITY;               // running max for q = fr (log2 domain)

    stage(0, 0);
    __syncthreads();
    char* const pbase = lds + 32768 + w * 2048;   // per-wave P[16 q][64 k] bf16, swizzled

    auto tile = [&](int kt, int cur) {
        if (kt < 15) stage(kt + 1, cur ^ 1);
        const char* kb = lds + cur * 8192;
        const char* vb = lds + 16384 + cur * 8192;

        // ---- S^T = K Q^T : lane (fr,fg) holds S[k=jb*16+fg*4+r][q=fr] ----
        f32x4 S[4];
        __builtin_amdgcn_s_setprio(1);
#pragma unroll
        for (int jb = 0; jb < 4; ++jb) {
            f32x4 a = {};
#pragma unroll
            for (int s = 0; s < 2; ++s) {
                const int row = jb * 16 + fr;
                const int c = s * 64 + fg * 16;
                const bf16x8 kf = *(const bf16x8*)(kb + row * 128 + (c ^ ((row & 7) << 4)));
                a = __builtin_amdgcn_mfma_f32_16x16x32_bf16(kf, qf[s], a, 0, 0, 0);
            }
            S[jb] = a;
        }
        __builtin_amdgcn_s_setprio(0);

        // ---- row max: max3 tree + cross-fg combine ----
        float tmax = fmax3_(S[0][0], S[0][1], S[0][2]);
        tmax = fmax3_(tmax, S[0][3], S[1][0]);
        tmax = fmax3_(tmax, S[1][1], S[1][2]);
        tmax = fmax3_(tmax, S[1][3], S[2][0]);
        tmax = fmax3_(tmax, S[2][1], S[2][2]);
        tmax = fmax3_(tmax, S[2][3], S[3][0]);
        tmax = fmax3_(tmax, S[3][1], S[3][2]);
        tmax = fmaxf(tmax, S[3][3]);
        tmax = fmaxf(tmax, __shfl_xor(tmax, 16));
        tmax = fmaxf(tmax, __shfl_xor(tmax, 32));

        // ---- defer-max: rescale only when a row grew > THR ----
        if (!__all(tmax - mrow <= RESCALE_THR_)) {
            const float mnew = fmaxf(mrow, tmax);
            const float corr = __builtin_amdgcn_exp2f(mrow - mnew);
            mrow = mnew;
#pragma unroll
            for (int r = 0; r < 4; ++r) {
                const float cr = __shfl(corr, fg * 4 + r);
                lacc[r] *= cr;
#pragma unroll
                for (int dvb = 0; dvb < 4; ++dvb) o[dvb][r] *= cr;
            }
        }

        // ---- P = 2^(S - m), pack (arithmetic 64b build), stage to per-wave LDS ----
#pragma unroll
        for (int jb = 0; jb < 4; ++jb) {
            const unsigned lo = cvt_pk_bf16(__builtin_amdgcn_exp2f(S[jb][0] - mrow),
                                            __builtin_amdgcn_exp2f(S[jb][1] - mrow));
            const unsigned hi = cvt_pk_bf16(__builtin_amdgcn_exp2f(S[jb][2] - mrow),
                                            __builtin_amdgcn_exp2f(S[jb][3] - mrow));
            const unsigned long long pv =
                (unsigned long long)lo | ((unsigned long long)hi << 32);
            *(unsigned long long*)(pbase + fr * 128 +
                                   ((jb * 32 + fg * 8) ^ ((fr & 7) << 4))) = pv;
        }

        // ---- fence: keep P ds_writes ordered before pf ds_reads ----
        asm volatile("" ::: "memory");

        // ---- O += P V ; l += P 1 (row-sum via MFMA) ----
        __builtin_amdgcn_s_setprio(1);
#pragma unroll
        for (int s = 0; s < 2; ++s) {
            const int pc = s * 64 + fg * 16;
            const bf16x8 pf = *(const bf16x8*)(pbase + fr * 128 + (pc ^ ((fr & 7) << 4)));
            lacc = __builtin_amdgcn_mfma_f32_16x16x32_bf16(pf, onesf, lacc, 0, 0, 0);
#pragma unroll
            for (int dvb = 0; dvb < 4; ++dvb) {
                const int vrow = dvb * 16 + fr;
                const bf16x8 vf = *(const bf16x8*)(vb + vrow * 128 + (pc ^ ((vrow & 7) << 4)));
                o[dvb] = __builtin_amdgcn_mfma_f32_16x16x32_bf16(pf, vf, o[dvb], 0, 0, 0);
            }
        }
        __builtin_amdgcn_s_setprio(0);
        __syncthreads();
    };

    for (int kt = 0; kt < 16; kt += 2) {
        tile(kt, 0);
        tile(kt + 1, 1);
    }

    // ---- epilogue: l already indexed by this lane's o-rows (q = fg*4+r) ----
#pragma unroll
    for (int r = 0; r < 4; ++r) {
        const float linv = 1.f / lacc[r];
        const size_t n = nbase + qrow0 + w * 16 + fg * 4 + r;
#pragma unroll
        for (int dvb = 0; dvb < 4; ++dvb)
            aoutb[n * 512 + h * 64 + dvb * 16 + fr] = bf_bits(o[dvb][r] * linv);
    }
}

extern "C" void kernel_launch(void* const* d_in, const int* in_sizes, int n_in,
                              void* d_out, int out_size, void* d_ws, size_t ws_size,
                              hipStream_t stream) {
    const float* x     = (const float*)d_in[0];
    const float* w_qkv = (const float*)d_in[1];
    const float* w_out = (const float*)d_in[2];
    const float* b_out = (const float*)d_in[3];
    float* out = (float*)d_out;

    char* ws = (char*)d_ws;
    ushort* qkvb  = (ushort*)ws;                                  // 48 MiB [16384,1536] (V cols unused)
    ushort* vT    = (ushort*)(ws + 50331648);                     // 16 MiB [128,64,1024]
    ushort* xb    = (ushort*)(ws + 50331648 + 16777216);          // 16 MiB
    ushort* aoutb = xb;                                           // aliased (xb dead after GEMM1)
    ushort* wqkvT = (ushort*)(ws + 50331648 + 33554432);          // 1.5 MiB
    ushort* woutT = (ushort*)(ws + 50331648 + 33554432 + 1572864);// 0.5 MiB

    const dim3 blk(256);
    // x cast + both weight transposes, one dispatch
    prep<<<dim3(9216), blk, 0, stream>>>(x, xb, w_qkv, wqkvT, w_out, woutT);
    // qkv (bf16) = x @ w_qkv ; V columns divert to vT
    gemm_bf16<<<dim3(1536), blk, 0, stream>>>(xb, wqkvT, nullptr, nullptr, qkvb, vT,
                                              16384, 1536, 512, 12);
    // attention (64-row q-tiles), XCD-swizzled — R14-frozen
    attn_mfma<<<dim3(2048), blk, 0, stream>>>(qkvb, vT, aoutb);
    // out = aout @ w_out + b_out (f32)
    gemm_bf16<<<dim3(512), blk, 0, stream>>>(aoutb, woutT, b_out, out, nullptr, nullptr,
                                             16384, 512, 512, 4);
}

// Round 19
// 131.525 us; speedup vs baseline: 1.0634x; 1.0282x over previous
//
#include <hip/hip_runtime.h>
#include <math.h>

// MHSA forward. x[16,1024,512]f32, w_qkv[512,1536], w_out[512,512], b_out[512].
// Round 19: R18-exact, single A/B variable: s_setprio REMOVED from attn (never isolated;
// added in R6 bundled). attn is 4-wave lockstep -> m190 regime (setprio null/negative),
// not m191's. Zero-risk edit class (hint instruction only — no ordering/layout change).
// ws: qkvb bf16[16384,1536] | vT bf16[128,64,1024] | xb/aoutb bf16[16384,512] | wqkvT | woutT

#define QSCALE_ 0.06376541773f        // 512^-0.5 * log2(e)
#define RESCALE_THR_ 8.0f             // log2-domain defer-max threshold

typedef float f32x4 __attribute__((ext_vector_type(4)));
typedef __bf16 bf16x8 __attribute__((ext_vector_type(8)));

static __device__ __forceinline__ ushort bf_bits(float f) {
    unsigned u = __builtin_bit_cast(unsigned, f);
    u += 0x7fffu + ((u >> 16) & 1u);          // RNE
    return (ushort)(u >> 16);
}
static __device__ __forceinline__ unsigned cvt_pk_bf16(float lo, float hi) {
    unsigned d;
    asm("v_cvt_pk_bf16_f32 %0, %1, %2" : "=v"(d) : "v"(lo), "v"(hi));
    return d;
}
static __device__ __forceinline__ float fmax3_(float a, float b, float c) {
    return fmaxf(fmaxf(a, b), c);
}
// bijective XCD swizzle: consecutive logical ids land on the same XCD (requires nwg%8==0)
static __device__ __forceinline__ int xcd_logical(int bid, int nwg) {
    return (bid & 7) * (nwg >> 3) + (bid >> 3);
}

#define GLDS16(gsrc, ldst)                                                              \
    __builtin_amdgcn_global_load_lds((const __attribute__((address_space(1))) void*)(gsrc), \
                                     (__attribute__((address_space(3))) void*)(ldst), 16, 0, 0)

// ---------------- prep: x cast (blocks 0..8191) + weight transposes (8192..9215) ----------------
__global__ __launch_bounds__(256) void prep(const float* __restrict__ x,
                                            ushort* __restrict__ xb,
                                            const float* __restrict__ wqkv,
                                            ushort* __restrict__ wqkvT,
                                            const float* __restrict__ wout,
                                            ushort* __restrict__ woutT) {
    if (blockIdx.x < 8192) {
        const int i = blockIdx.x * 256 + threadIdx.x;   // 2097152 float4's
        const float4 v = ((const float4*)x)[i];
        ushort4 o;
        o.x = bf_bits(v.x); o.y = bf_bits(v.y); o.z = bf_bits(v.z); o.w = bf_bits(v.w);
        ((ushort4*)xb)[i] = o;
        return;
    }
    __shared__ float t[32][33];
    const int tx = threadIdx.x & 31, ty = threadIdx.x >> 5;
    const float* in;
    ushort* out;
    int n0, k0, N;
    float scale;
    int scaleRows;
    const int bid = blockIdx.x - 8192;
    if (bid < 768) {
        in = wqkv; out = wqkvT; N = 1536;
        n0 = (bid % 48) * 32; k0 = (bid / 48) * 32;
        scale = QSCALE_; scaleRows = 512;
    } else {
        in = wout; out = woutT; N = 512;
        const int b2 = bid - 768;
        n0 = (b2 % 16) * 32; k0 = (b2 / 16) * 32;
        scale = 1.f; scaleRows = 0;
    }
    for (int i = ty; i < 32; i += 8)
        t[i][tx] = in[(size_t)(k0 + i) * N + n0 + tx];
    __syncthreads();
    for (int i = ty; i < 32; i += 8) {
        const float s = (n0 + i < scaleRows) ? scale : 1.f;
        out[(size_t)(n0 + i) * 512 + k0 + tx] = bf_bits(t[tx][i] * s);
    }
}

// ---------------- C = A[M,K] @ BT[N,K]^T (+bias), bf16 MFMA, 128x128, dbuf ----------------
// R12/R14-proven schedule: stage(t+1) issued FIRST, then frag reads. Do not reorder.
// Cb path: cols >= 1024 (V region) divert to vT[bh=128][dv=64][n=1024] (when VT != null).
__global__ __launch_bounds__(256) void gemm_bf16(const ushort* __restrict__ A,
                                                 const ushort* __restrict__ BT,
                                                 const float* __restrict__ bias,
                                                 float* __restrict__ C,
                                                 ushort* __restrict__ Cb,
                                                 ushort* __restrict__ VT,
                                                 int M, int N, int K, int nx) {
    __shared__ __align__(16) char lds[32768];
    const int logical = xcd_logical(blockIdx.x, gridDim.x);
    const int bx = logical % nx;
    const int by = logical / nx;
    const int tid = threadIdx.x;
    const int lane = tid & 63;
    const int w = tid >> 6;
    const int wr = w >> 1, wc = w & 1;
    const int fr = lane & 15;
    const int fg = lane >> 4;
    const int rowBase = by * 128;
    const int colBase = bx * 128;

    auto stageG = [&](int k0, int buf) {
#pragma unroll
        for (int r = 0; r < 2; ++r) {
            const unsigned boff = r * 4096u + w * 1024u + lane * 16u;
            const unsigned row = boff >> 6;
            const unsigned ke = (boff & 63u) >> 1;
            GLDS16(A + (size_t)(rowBase + row) * K + k0 + ke,
                   lds + buf * 8192 + r * 4096 + w * 1024);
            GLDS16(BT + (size_t)(colBase + row) * K + k0 + ke,
                   lds + 16384 + buf * 8192 + r * 4096 + w * 1024);
        }
    };

    f32x4 acc[4][4] = {};

    stageG(0, 0);
    __syncthreads();
    int cur = 0;
    const int nsteps = K / 32;

    for (int s = 0; s < nsteps; ++s) {
        if (s + 1 < nsteps) stageG((s + 1) * 32, cur ^ 1);
        const char* ab = lds + cur * 8192;
        const char* bb = lds + 16384 + cur * 8192;

        bf16x8 a_frag[4], b_frag[4];
#pragma unroll
        for (int mi = 0; mi < 4; ++mi)
            a_frag[mi] = *(const bf16x8*)(ab + (wr * 64 + mi * 16 + fr) * 64 + fg * 16);
#pragma unroll
        for (int ni = 0; ni < 4; ++ni)
            b_frag[ni] = *(const bf16x8*)(bb + (wc * 64 + ni * 16 + fr) * 64 + fg * 16);
#pragma unroll
        for (int mi = 0; mi < 4; ++mi)
#pragma unroll
            for (int ni = 0; ni < 4; ++ni)
                acc[mi][ni] = __builtin_amdgcn_mfma_f32_16x16x32_bf16(a_frag[mi], b_frag[ni],
                                                                      acc[mi][ni], 0, 0, 0);
        __syncthreads();
        cur ^= 1;
    }

#pragma unroll
    for (int ni = 0; ni < 4; ++ni) {
        const int col = colBase + wc * 64 + ni * 16 + fr;
        const float bv = bias ? bias[col] : 0.f;
#pragma unroll
        for (int mi = 0; mi < 4; ++mi) {
            const int row0 = rowBase + wr * 64 + mi * 16 + fg * 4;
            if (Cb) {
                if (VT && col >= 1024) {
                    const int hd = col - 1024;
                    const size_t vb = ((size_t)((row0 >> 10) * 8 + (hd >> 6)) * 64 + (hd & 63)) * 1024
                                      + (row0 & 1023);
                    ushort4 pk4;
                    pk4.x = bf_bits(acc[mi][ni][0]);
                    pk4.y = bf_bits(acc[mi][ni][1]);
                    pk4.z = bf_bits(acc[mi][ni][2]);
                    pk4.w = bf_bits(acc[mi][ni][3]);
                    *(ushort4*)(VT + vb) = pk4;
                } else {
#pragma unroll
                    for (int q = 0; q < 4; ++q)
                        Cb[(size_t)(row0 + q) * N + col] = bf_bits(acc[mi][ni][q]);
                }
            } else {
#pragma unroll
                for (int q = 0; q < 4; ++q)
                    C[(size_t)(row0 + q) * N + col] = acc[mi][ni][q] + bv;
            }
        }
    }
}

// ---------------- MFMA flash attention (R14 schedule, setprio removed) ----------------
// 4 waves, 256 thr, 64-row Q tile, stage(t+1) FIRST in tile(). 1-D grid 2048, XCD-swizzled.
__global__ __launch_bounds__(256) void attn_mfma(const ushort* __restrict__ qkv,
                                                 const ushort* __restrict__ vT,
                                                 ushort* __restrict__ aoutb) {
    __shared__ __align__(16) char lds[40960];  // K:[2]x8KB @0 ; VT:[2]x8KB @16384 ; P: @32768 + w*2048
    const int logical = xcd_logical(blockIdx.x, gridDim.x);
    const int qt = logical & 15;
    const int bh = logical >> 4;
    const int b = bh >> 3, h = bh & 7;
    const int tid = threadIdx.x;
    const int lane = tid & 63;
    const int w = tid >> 6;
    const int fr = lane & 15;
    const int fg = lane >> 4;

    const size_t nbase = (size_t)b * 1024;
    const int qrow0 = qt * 64;

    bf16x8 qf[2];
    {
        const size_t qa = (nbase + qrow0 + w * 16 + fr) * 1536 + h * 64;
        qf[0] = *(const bf16x8*)(qkv + qa + fg * 8);
        qf[1] = *(const bf16x8*)(qkv + qa + 32 + fg * 8);
    }

    bf16x8 onesf;
#pragma unroll
    for (int e = 0; e < 8; ++e) onesf[e] = __builtin_bit_cast(__bf16, (ushort)0x3F80);

    const int srow = w * 16 + (lane >> 3);
    const int slot = lane & 7;
    auto stage = [&](int kt, int buf) {
        char* kd = lds + buf * 8192;
        char* vd = lds + 16384 + buf * 8192;
#pragma unroll
        for (int r = 0; r < 2; ++r) {
            const int row = srow + r * 8;
            const int sw = slot ^ (row & 7);
            GLDS16(qkv + (nbase + kt * 64 + row) * 1536 + 512 + h * 64 + sw * 8,
                   kd + (w * 2 + r) * 1024);
            GLDS16(vT + ((size_t)bh * 64 + row) * 1024 + kt * 64 + sw * 8,
                   vd + (w * 2 + r) * 1024);
        }
    };

    f32x4 o[4] = {};                      // o[dvb]: q = fg*4+r, dv = dvb*16+fr
    f32x4 lacc = {};                      // l[q = fg*4+r]
    float mrow = -INFINITY;               // running max for q = fr (log2 domain)

    stage(0, 0);
    __syncthreads();
    char* const pbase = lds + 32768 + w * 2048;   // per-wave P[16 q][64 k] bf16, swizzled

    auto tile = [&](int kt, int cur) {
        if (kt < 15) stage(kt + 1, cur ^ 1);
        const char* kb = lds + cur * 8192;
        const char* vb = lds + 16384 + cur * 8192;

        // ---- S^T = K Q^T : lane (fr,fg) holds S[k=jb*16+fg*4+r][q=fr] ----
        f32x4 S[4];
#pragma unroll
        for (int jb = 0; jb < 4; ++jb) {
            f32x4 a = {};
#pragma unroll
            for (int s = 0; s < 2; ++s) {
                const int row = jb * 16 + fr;
                const int c = s * 64 + fg * 16;
                const bf16x8 kf = *(const bf16x8*)(kb + row * 128 + (c ^ ((row & 7) << 4)));
                a = __builtin_amdgcn_mfma_f32_16x16x32_bf16(kf, qf[s], a, 0, 0, 0);
            }
            S[jb] = a;
        }

        // ---- row max: max3 tree + cross-fg combine ----
        float tmax = fmax3_(S[0][0], S[0][1], S[0][2]);
        tmax = fmax3_(tmax, S[0][3], S[1][0]);
        tmax = fmax3_(tmax, S[1][1], S[1][2]);
        tmax = fmax3_(tmax, S[1][3], S[2][0]);
        tmax = fmax3_(tmax, S[2][1], S[2][2]);
        tmax = fmax3_(tmax, S[2][3], S[3][0]);
        tmax = fmax3_(tmax, S[3][1], S[3][2]);
        tmax = fmaxf(tmax, S[3][3]);
        tmax = fmaxf(tmax, __shfl_xor(tmax, 16));
        tmax = fmaxf(tmax, __shfl_xor(tmax, 32));

        // ---- defer-max: rescale only when a row grew > THR ----
        if (!__all(tmax - mrow <= RESCALE_THR_)) {
            const float mnew = fmaxf(mrow, tmax);
            const float corr = __builtin_amdgcn_exp2f(mrow - mnew);
            mrow = mnew;
#pragma unroll
            for (int r = 0; r < 4; ++r) {
                const float cr = __shfl(corr, fg * 4 + r);
                lacc[r] *= cr;
#pragma unroll
                for (int dvb = 0; dvb < 4; ++dvb) o[dvb][r] *= cr;
            }
        }

        // ---- P = 2^(S - m), pack (arithmetic 64b build), stage to per-wave LDS ----
#pragma unroll
        for (int jb = 0; jb < 4; ++jb) {
            const unsigned lo = cvt_pk_bf16(__builtin_amdgcn_exp2f(S[jb][0] - mrow),
                                            __builtin_amdgcn_exp2f(S[jb][1] - mrow));
            const unsigned hi = cvt_pk_bf16(__builtin_amdgcn_exp2f(S[jb][2] - mrow),
                                            __builtin_amdgcn_exp2f(S[jb][3] - mrow));
            const unsigned long long pv =
                (unsigned long long)lo | ((unsigned long long)hi << 32);
            *(unsigned long long*)(pbase + fr * 128 +
                                   ((jb * 32 + fg * 8) ^ ((fr & 7) << 4))) = pv;
        }

        // ---- fence: keep P ds_writes ordered before pf ds_reads ----
        asm volatile("" ::: "memory");

        // ---- O += P V ; l += P 1 (row-sum via MFMA) ----
#pragma unroll
        for (int s = 0; s < 2; ++s) {
            const int pc = s * 64 + fg * 16;
            const bf16x8 pf = *(const bf16x8*)(pbase + fr * 128 + (pc ^ ((fr & 7) << 4)));
            lacc = __builtin_amdgcn_mfma_f32_16x16x32_bf16(pf, onesf, lacc, 0, 0, 0);
#pragma unroll
            for (int dvb = 0; dvb < 4; ++dvb) {
                const int vrow = dvb * 16 + fr;
                const bf16x8 vf = *(const bf16x8*)(vb + vrow * 128 + (pc ^ ((vrow & 7) << 4)));
                o[dvb] = __builtin_amdgcn_mfma_f32_16x16x32_bf16(pf, vf, o[dvb], 0, 0, 0);
            }
        }
        __syncthreads();
    };

    for (int kt = 0; kt < 16; kt += 2) {
        tile(kt, 0);
        tile(kt + 1, 1);
    }

    // ---- epilogue: l already indexed by this lane's o-rows (q = fg*4+r) ----
#pragma unroll
    for (int r = 0; r < 4; ++r) {
        const float linv = 1.f / lacc[r];
        const size_t n = nbase + qrow0 + w * 16 + fg * 4 + r;
#pragma unroll
        for (int dvb = 0; dvb < 4; ++dvb)
            aoutb[n * 512 + h * 64 + dvb * 16 + fr] = bf_bits(o[dvb][r] * linv);
    }
}

extern "C" void kernel_launch(void* const* d_in, const int* in_sizes, int n_in,
                              void* d_out, int out_size, void* d_ws, size_t ws_size,
                              hipStream_t stream) {
    const float* x     = (const float*)d_in[0];
    const float* w_qkv = (const float*)d_in[1];
    const float* w_out = (const float*)d_in[2];
    const float* b_out = (const float*)d_in[3];
    float* out = (float*)d_out;

    char* ws = (char*)d_ws;
    ushort* qkvb  = (ushort*)ws;                                  // 48 MiB [16384,1536] (V cols unused)
    ushort* vT    = (ushort*)(ws + 50331648);                     // 16 MiB [128,64,1024]
    ushort* xb    = (ushort*)(ws + 50331648 + 16777216);          // 16 MiB
    ushort* aoutb = xb;                                           // aliased (xb dead after GEMM1)
    ushort* wqkvT = (ushort*)(ws + 50331648 + 33554432);          // 1.5 MiB
    ushort* woutT = (ushort*)(ws + 50331648 + 33554432 + 1572864);// 0.5 MiB

    const dim3 blk(256);
    // x cast + both weight transposes, one dispatch
    prep<<<dim3(9216), blk, 0, stream>>>(x, xb, w_qkv, wqkvT, w_out, woutT);
    // qkv (bf16) = x @ w_qkv ; V columns divert to vT
    gemm_bf16<<<dim3(1536), blk, 0, stream>>>(xb, wqkvT, nullptr, nullptr, qkvb, vT,
                                              16384, 1536, 512, 12);
    // attention (64-row q-tiles), XCD-swizzled
    attn_mfma<<<dim3(2048), blk, 0, stream>>>(qkvb, vT, aoutb);
    // out = aout @ w_out + b_out (f32)
    gemm_bf16<<<dim3(512), blk, 0, stream>>>(aoutb, woutT, b_out, out, nullptr, nullptr,
                                             16384, 512, 512, 4);
}

// Round 20
// 131.105 us; speedup vs baseline: 1.0669x; 1.0032x over previous
//
#include <hip/hip_runtime.h>
#include <math.h>

// MHSA forward. x[16,1024,512]f32, w_qkv[512,1536], w_out[512,512], b_out[512].
// Round 20 (FINAL): R19-exact verification run. 131.5us config: prep (fused cast+
// transposes) -> GEMM1 128x128/4-wave dbuf stage-first + XCD swizzle (bf16 qkv + vT
// divert) -> attn 4-wave/64-row frozen schedule (swapped QK^T, in-reg softmax, exp2
// domain, defer-max, MFMA row-sum, NO setprio: VGPR 64 -> 8 waves/SIMD eligible)
// -> GEMM2 + bias. Session ledger: 2085 -> 131.5 us (15.9x).
// ws: qkvb bf16[16384,1536] | vT bf16[128,64,1024] | xb/aoutb bf16[16384,512] | wqkvT | woutT

#define QSCALE_ 0.06376541773f        // 512^-0.5 * log2(e)
#define RESCALE_THR_ 8.0f             // log2-domain defer-max threshold

typedef float f32x4 __attribute__((ext_vector_type(4)));
typedef __bf16 bf16x8 __attribute__((ext_vector_type(8)));

static __device__ __forceinline__ ushort bf_bits(float f) {
    unsigned u = __builtin_bit_cast(unsigned, f);
    u += 0x7fffu + ((u >> 16) & 1u);          // RNE
    return (ushort)(u >> 16);
}
static __device__ __forceinline__ unsigned cvt_pk_bf16(float lo, float hi) {
    unsigned d;
    asm("v_cvt_pk_bf16_f32 %0, %1, %2" : "=v"(d) : "v"(lo), "v"(hi));
    return d;
}
static __device__ __forceinline__ float fmax3_(float a, float b, float c) {
    return fmaxf(fmaxf(a, b), c);
}
// bijective XCD swizzle: consecutive logical ids land on the same XCD (requires nwg%8==0)
static __device__ __forceinline__ int xcd_logical(int bid, int nwg) {
    return (bid & 7) * (nwg >> 3) + (bid >> 3);
}

#define GLDS16(gsrc, ldst)                                                              \
    __builtin_amdgcn_global_load_lds((const __attribute__((address_space(1))) void*)(gsrc), \
                                     (__attribute__((address_space(3))) void*)(ldst), 16, 0, 0)

// ---------------- prep: x cast (blocks 0..8191) + weight transposes (8192..9215) ----------------
__global__ __launch_bounds__(256) void prep(const float* __restrict__ x,
                                            ushort* __restrict__ xb,
                                            const float* __restrict__ wqkv,
                                            ushort* __restrict__ wqkvT,
                                            const float* __restrict__ wout,
                                            ushort* __restrict__ woutT) {
    if (blockIdx.x < 8192) {
        const int i = blockIdx.x * 256 + threadIdx.x;   // 2097152 float4's
        const float4 v = ((const float4*)x)[i];
        ushort4 o;
        o.x = bf_bits(v.x); o.y = bf_bits(v.y); o.z = bf_bits(v.z); o.w = bf_bits(v.w);
        ((ushort4*)xb)[i] = o;
        return;
    }
    __shared__ float t[32][33];
    const int tx = threadIdx.x & 31, ty = threadIdx.x >> 5;
    const float* in;
    ushort* out;
    int n0, k0, N;
    float scale;
    int scaleRows;
    const int bid = blockIdx.x - 8192;
    if (bid < 768) {
        in = wqkv; out = wqkvT; N = 1536;
        n0 = (bid % 48) * 32; k0 = (bid / 48) * 32;
        scale = QSCALE_; scaleRows = 512;
    } else {
        in = wout; out = woutT; N = 512;
        const int b2 = bid - 768;
        n0 = (b2 % 16) * 32; k0 = (b2 / 16) * 32;
        scale = 1.f; scaleRows = 0;
    }
    for (int i = ty; i < 32; i += 8)
        t[i][tx] = in[(size_t)(k0 + i) * N + n0 + tx];
    __syncthreads();
    for (int i = ty; i < 32; i += 8) {
        const float s = (n0 + i < scaleRows) ? scale : 1.f;
        out[(size_t)(n0 + i) * 512 + k0 + tx] = bf_bits(t[tx][i] * s);
    }
}

// ---------------- C = A[M,K] @ BT[N,K]^T (+bias), bf16 MFMA, 128x128, dbuf ----------------
// R12/R14-proven schedule: stage(t+1) issued FIRST, then frag reads. Do not reorder.
// Cb path: cols >= 1024 (V region) divert to vT[bh=128][dv=64][n=1024] (when VT != null).
__global__ __launch_bounds__(256) void gemm_bf16(const ushort* __restrict__ A,
                                                 const ushort* __restrict__ BT,
                                                 const float* __restrict__ bias,
                                                 float* __restrict__ C,
                                                 ushort* __restrict__ Cb,
                                                 ushort* __restrict__ VT,
                                                 int M, int N, int K, int nx) {
    __shared__ __align__(16) char lds[32768];
    const int logical = xcd_logical(blockIdx.x, gridDim.x);
    const int bx = logical % nx;
    const int by = logical / nx;
    const int tid = threadIdx.x;
    const int lane = tid & 63;
    const int w = tid >> 6;
    const int wr = w >> 1, wc = w & 1;
    const int fr = lane & 15;
    const int fg = lane >> 4;
    const int rowBase = by * 128;
    const int colBase = bx * 128;

    auto stageG = [&](int k0, int buf) {
#pragma unroll
        for (int r = 0; r < 2; ++r) {
            const unsigned boff = r * 4096u + w * 1024u + lane * 16u;
            const unsigned row = boff >> 6;
            const unsigned ke = (boff & 63u) >> 1;
            GLDS16(A + (size_t)(rowBase + row) * K + k0 + ke,
                   lds + buf * 8192 + r * 4096 + w * 1024);
            GLDS16(BT + (size_t)(colBase + row) * K + k0 + ke,
                   lds + 16384 + buf * 8192 + r * 4096 + w * 1024);
        }
    };

    f32x4 acc[4][4] = {};

    stageG(0, 0);
    __syncthreads();
    int cur = 0;
    const int nsteps = K / 32;

    for (int s = 0; s < nsteps; ++s) {
        if (s + 1 < nsteps) stageG((s + 1) * 32, cur ^ 1);
        const char* ab = lds + cur * 8192;
        const char* bb = lds + 16384 + cur * 8192;

        bf16x8 a_frag[4], b_frag[4];
#pragma unroll
        for (int mi = 0; mi < 4; ++mi)
            a_frag[mi] = *(const bf16x8*)(ab + (wr * 64 + mi * 16 + fr) * 64 + fg * 16);
#pragma unroll
        for (int ni = 0; ni < 4; ++ni)
            b_frag[ni] = *(const bf16x8*)(bb + (wc * 64 + ni * 16 + fr) * 64 + fg * 16);
#pragma unroll
        for (int mi = 0; mi < 4; ++mi)
#pragma unroll
            for (int ni = 0; ni < 4; ++ni)
                acc[mi][ni] = __builtin_amdgcn_mfma_f32_16x16x32_bf16(a_frag[mi], b_frag[ni],
                                                                      acc[mi][ni], 0, 0, 0);
        __syncthreads();
        cur ^= 1;
    }

#pragma unroll
    for (int ni = 0; ni < 4; ++ni) {
        const int col = colBase + wc * 64 + ni * 16 + fr;
        const float bv = bias ? bias[col] : 0.f;
#pragma unroll
        for (int mi = 0; mi < 4; ++mi) {
            const int row0 = rowBase + wr * 64 + mi * 16 + fg * 4;
            if (Cb) {
                if (VT && col >= 1024) {
                    const int hd = col - 1024;
                    const size_t vb = ((size_t)((row0 >> 10) * 8 + (hd >> 6)) * 64 + (hd & 63)) * 1024
                                      + (row0 & 1023);
                    ushort4 pk4;
                    pk4.x = bf_bits(acc[mi][ni][0]);
                    pk4.y = bf_bits(acc[mi][ni][1]);
                    pk4.z = bf_bits(acc[mi][ni][2]);
                    pk4.w = bf_bits(acc[mi][ni][3]);
                    *(ushort4*)(VT + vb) = pk4;
                } else {
#pragma unroll
                    for (int q = 0; q < 4; ++q)
                        Cb[(size_t)(row0 + q) * N + col] = bf_bits(acc[mi][ni][q]);
                }
            } else {
#pragma unroll
                for (int q = 0; q < 4; ++q)
                    C[(size_t)(row0 + q) * N + col] = acc[mi][ni][q] + bv;
            }
        }
    }
}

// ---------------- MFMA flash attention (frozen schedule, no setprio) ----------------
// 4 waves, 256 thr, 64-row Q tile, stage(t+1) FIRST in tile(). 1-D grid 2048, XCD-swizzled.
__global__ __launch_bounds__(256) void attn_mfma(const ushort* __restrict__ qkv,
                                                 const ushort* __restrict__ vT,
                                                 ushort* __restrict__ aoutb) {
    __shared__ __align__(16) char lds[40960];  // K:[2]x8KB @0 ; VT:[2]x8KB @16384 ; P: @32768 + w*2048
    const int logical = xcd_logical(blockIdx.x, gridDim.x);
    const int qt = logical & 15;
    const int bh = logical >> 4;
    const int b = bh >> 3, h = bh & 7;
    const int tid = threadIdx.x;
    const int lane = tid & 63;
    const int w = tid >> 6;
    const int fr = lane & 15;
    const int fg = lane >> 4;

    const size_t nbase = (size_t)b * 1024;
    const int qrow0 = qt * 64;

    bf16x8 qf[2];
    {
        const size_t qa = (nbase + qrow0 + w * 16 + fr) * 1536 + h * 64;
        qf[0] = *(const bf16x8*)(qkv + qa + fg * 8);
        qf[1] = *(const bf16x8*)(qkv + qa + 32 + fg * 8);
    }

    bf16x8 onesf;
#pragma unroll
    for (int e = 0; e < 8; ++e) onesf[e] = __builtin_bit_cast(__bf16, (ushort)0x3F80);

    const int srow = w * 16 + (lane >> 3);
    const int slot = lane & 7;
    auto stage = [&](int kt, int buf) {
        char* kd = lds + buf * 8192;
        char* vd = lds + 16384 + buf * 8192;
#pragma unroll
        for (int r = 0; r < 2; ++r) {
            const int row = srow + r * 8;
            const int sw = slot ^ (row & 7);
            GLDS16(qkv + (nbase + kt * 64 + row) * 1536 + 512 + h * 64 + sw * 8,
                   kd + (w * 2 + r) * 1024);
            GLDS16(vT + ((size_t)bh * 64 + row) * 1024 + kt * 64 + sw * 8,
                   vd + (w * 2 + r) * 1024);
        }
    };

    f32x4 o[4] = {};                      // o[dvb]: q = fg*4+r, dv = dvb*16+fr
    f32x4 lacc = {};                      // l[q = fg*4+r]
    float mrow = -INFINITY;               // running max for q = fr (log2 domain)

    stage(0, 0);
    __syncthreads();
    char* const pbase = lds + 32768 + w * 2048;   // per-wave P[16 q][64 k] bf16, swizzled

    auto tile = [&](int kt, int cur) {
        if (kt < 15) stage(kt + 1, cur ^ 1);
        const char* kb = lds + cur * 8192;
        const char* vb = lds + 16384 + cur * 8192;

        // ---- S^T = K Q^T : lane (fr,fg) holds S[k=jb*16+fg*4+r][q=fr] ----
        f32x4 S[4];
#pragma unroll
        for (int jb = 0; jb < 4; ++jb) {
            f32x4 a = {};
#pragma unroll
            for (int s = 0; s < 2; ++s) {
                const int row = jb * 16 + fr;
                const int c = s * 64 + fg * 16;
                const bf16x8 kf = *(const bf16x8*)(kb + row * 128 + (c ^ ((row & 7) << 4)));
                a = __builtin_amdgcn_mfma_f32_16x16x32_bf16(kf, qf[s], a, 0, 0, 0);
            }
            S[jb] = a;
        }

        // ---- row max: max3 tree + cross-fg combine ----
        float tmax = fmax3_(S[0][0], S[0][1], S[0][2]);
        tmax = fmax3_(tmax, S[0][3], S[1][0]);
        tmax = fmax3_(tmax, S[1][1], S[1][2]);
        tmax = fmax3_(tmax, S[1][3], S[2][0]);
        tmax = fmax3_(tmax, S[2][1], S[2][2]);
        tmax = fmax3_(tmax, S[2][3], S[3][0]);
        tmax = fmax3_(tmax, S[3][1], S[3][2]);
        tmax = fmaxf(tmax, S[3][3]);
        tmax = fmaxf(tmax, __shfl_xor(tmax, 16));
        tmax = fmaxf(tmax, __shfl_xor(tmax, 32));

        // ---- defer-max: rescale only when a row grew > THR ----
        if (!__all(tmax - mrow <= RESCALE_THR_)) {
            const float mnew = fmaxf(mrow, tmax);
            const float corr = __builtin_amdgcn_exp2f(mrow - mnew);
            mrow = mnew;
#pragma unroll
            for (int r = 0; r < 4; ++r) {
                const float cr = __shfl(corr, fg * 4 + r);
                lacc[r] *= cr;
#pragma unroll
                for (int dvb = 0; dvb < 4; ++dvb) o[dvb][r] *= cr;
            }
        }

        // ---- P = 2^(S - m), pack (arithmetic 64b build), stage to per-wave LDS ----
#pragma unroll
        for (int jb = 0; jb < 4; ++jb) {
            const unsigned lo = cvt_pk_bf16(__builtin_amdgcn_exp2f(S[jb][0] - mrow),
                                            __builtin_amdgcn_exp2f(S[jb][1] - mrow));
            const unsigned hi = cvt_pk_bf16(__builtin_amdgcn_exp2f(S[jb][2] - mrow),
                                            __builtin_amdgcn_exp2f(S[jb][3] - mrow));
            const unsigned long long pv =
                (unsigned long long)lo | ((unsigned long long)hi << 32);
            *(unsigned long long*)(pbase + fr * 128 +
                                   ((jb * 32 + fg * 8) ^ ((fr & 7) << 4))) = pv;
        }

        // ---- fence: keep P ds_writes ordered before pf ds_reads ----
        asm volatile("" ::: "memory");

        // ---- O += P V ; l += P 1 (row-sum via MFMA) ----
#pragma unroll
        for (int s = 0; s < 2; ++s) {
            const int pc = s * 64 + fg * 16;
            const bf16x8 pf = *(const bf16x8*)(pbase + fr * 128 + (pc ^ ((fr & 7) << 4)));
            lacc = __builtin_amdgcn_mfma_f32_16x16x32_bf16(pf, onesf, lacc, 0, 0, 0);
#pragma unroll
            for (int dvb = 0; dvb < 4; ++dvb) {
                const int vrow = dvb * 16 + fr;
                const bf16x8 vf = *(const bf16x8*)(vb + vrow * 128 + (pc ^ ((vrow & 7) << 4)));
                o[dvb] = __builtin_amdgcn_mfma_f32_16x16x32_bf16(pf, vf, o[dvb], 0, 0, 0);
            }
        }
        __syncthreads();
    };

    for (int kt = 0; kt < 16; kt += 2) {
        tile(kt, 0);
        tile(kt + 1, 1);
    }

    // ---- epilogue: l already indexed by this lane's o-rows (q = fg*4+r) ----
#pragma unroll
    for (int r = 0; r < 4; ++r) {
        const float linv = 1.f / lacc[r];
        const size_t n = nbase + qrow0 + w * 16 + fg * 4 + r;
#pragma unroll
        for (int dvb = 0; dvb < 4; ++dvb)
            aoutb[n * 512 + h * 64 + dvb * 16 + fr] = bf_bits(o[dvb][r] * linv);
    }
}

extern "C" void kernel_launch(void* const* d_in, const int* in_sizes, int n_in,
                              void* d_out, int out_size, void* d_ws, size_t ws_size,
                              hipStream_t stream) {
    const float* x     = (const float*)d_in[0];
    const float* w_qkv = (const float*)d_in[1];
    const float* w_out = (const float*)d_in[2];
    const float* b_out = (const float*)d_in[3];
    float* out = (float*)d_out;

    char* ws = (char*)d_ws;
    ushort* qkvb  = (ushort*)ws;                                  // 48 MiB [16384,1536] (V cols unused)
    ushort* vT    = (ushort*)(ws + 50331648);                     // 16 MiB [128,64,1024]
    ushort* xb    = (ushort*)(ws + 50331648 + 16777216);          // 16 MiB
    ushort* aoutb = xb;                                           // aliased (xb dead after GEMM1)
    ushort* wqkvT = (ushort*)(ws + 50331648 + 33554432);          // 1.5 MiB
    ushort* woutT = (ushort*)(ws + 50331648 + 33554432 + 1572864);// 0.5 MiB

    const dim3 blk(256);
    // x cast + both weight transposes, one dispatch
    prep<<<dim3(9216), blk, 0, stream>>>(x, xb, w_qkv, wqkvT, w_out, woutT);
    // qkv (bf16) = x @ w_qkv ; V columns divert to vT
    gemm_bf16<<<dim3(1536), blk, 0, stream>>>(xb, wqkvT, nullptr, nullptr, qkvb, vT,
                                              16384, 1536, 512, 12);
    // attention (64-row q-tiles), XCD-swizzled
    attn_mfma<<<dim3(2048), blk, 0, stream>>>(qkvb, vT, aoutb);
    // out = aout @ w_out + b_out (f32)
    gemm_bf16<<<dim3(512), blk, 0, stream>>>(aoutb, woutT, b_out, out, nullptr, nullptr,
                                             16384, 512, 512, 4);
}